// Round 2
// baseline (821.193 us; speedup 1.0000x reference)
//
#include <hip/hip_runtime.h>
#include <hip/hip_cooperative_groups.h>
#include <math.h>

namespace cg = cooperative_groups;

#define DD 2048
#define HH 4096
#define NSTEPS 16
#define KK 4

// workspace float offsets
#define OFF_CAT    0        // h[4096], l[2048], conv[1] (6145 used, pad 6400)
#define OFF_GI_H   6400     // 12288
#define OFF_GH_H   18688    // 12288
#define OFF_GI_L   30976    // 6144
#define OFF_GH_L   37120    // 6144
#define OFF_DIR    43264    // 2048
#define OFF_RES    45312    // 2048
#define OFF_RESULT 47360    // 2048
#define OFF_SCAL   49408    // [0]cum [1]weight [2]best [3]mom [4]active [5]do_reset [6]raw_conv
#define OFF_XCAT   49472    // [q(2048), l(2048)]

static __device__ __forceinline__ float sigf(float x) { return 1.0f / (1.0f + expf(-x)); }

static __device__ __forceinline__ float wred(float s) {
#pragma unroll
  for (int off = 32; off; off >>= 1) s += __shfl_down(s, off);
  return s;
}

// 4-deep unrolled float4 row-dot: 8 loads in flight before the fma chain.
// n4 must be a multiple of 256 (512 or 1024 here).
static __device__ __forceinline__ float dot4(const float4* __restrict__ Wr,
                                             const float4* __restrict__ x,
                                             int n4, int lane) {
  float s = 0.0f;
  for (int i = lane; i + 192 < n4; i += 256) {
    float4 w0 = Wr[i], w1 = Wr[i + 64], w2 = Wr[i + 128], w3 = Wr[i + 192];
    float4 v0 = x[i],  v1 = x[i + 64],  v2 = x[i + 128],  v3 = x[i + 192];
    s = fmaf(w0.x, v0.x, s); s = fmaf(w0.y, v0.y, s);
    s = fmaf(w0.z, v0.z, s); s = fmaf(w0.w, v0.w, s);
    s = fmaf(w1.x, v1.x, s); s = fmaf(w1.y, v1.y, s);
    s = fmaf(w1.z, v1.z, s); s = fmaf(w1.w, v1.w, s);
    s = fmaf(w2.x, v2.x, s); s = fmaf(w2.y, v2.y, s);
    s = fmaf(w2.z, v2.z, s); s = fmaf(w2.w, v2.w, s);
    s = fmaf(w3.x, v3.x, s); s = fmaf(w3.y, v3.y, s);
    s = fmaf(w3.z, v3.z, s); s = fmaf(w3.w, v3.w, s);
  }
  return wred(s);
}

// ---------------- cooperative whole-recurrence kernel ----------------
__global__ __launch_bounds__(256) void k_loop(
    const float* __restrict__ query,
    const float* __restrict__ h_wih, const float* __restrict__ h_whh,
    const float* __restrict__ h_bih, const float* __restrict__ h_bhh,
    const float* __restrict__ l_wih, const float* __restrict__ l_whh,
    const float* __restrict__ l_bih, const float* __restrict__ l_bhh,
    const float* __restrict__ dir_w, const float* __restrict__ dir_b,
    const float* __restrict__ conv_w, const float* __restrict__ conv_b,
    const float* __restrict__ out_w, const float* __restrict__ out_b,
    const float* __restrict__ halt_w, const float* __restrict__ halt_b,
    const float* __restrict__ reset_w, const float* __restrict__ reset_b,
    const float* __restrict__ init_w, const float* __restrict__ init_b,
    float* __restrict__ ws, float* __restrict__ out) {
  cg::grid_group grid = cg::this_grid();
  const int tid  = threadIdx.x;
  const int lane = tid & 63;
  const int wib  = tid >> 6;
  const int nw   = (int)(gridDim.x << 2);
  const int wid  = (int)((blockIdx.x << 2) | wib);
  const int gtid = (int)(blockIdx.x * 256 + tid);
  const int gsz  = (int)(gridDim.x * 256);

  float* cat    = ws + OFF_CAT;        // h[0..HH), l[HH..HH+DD)
  float* gi_h   = ws + OFF_GI_H;
  float* gh_h   = ws + OFF_GH_H;
  float* gi_l   = ws + OFF_GI_L;
  float* gh_l   = ws + OFF_GH_L;
  float* dir    = ws + OFF_DIR;
  float* res    = ws + OFF_RES;
  float* result = ws + OFF_RESULT;
  float* scal   = ws + OFF_SCAL;
  float* xcat   = ws + OFF_XCAT;
  volatile float* vs = scal;

  // ---- init ----
  for (int i = gtid; i < 6400; i += gsz) cat[i] = 0.0f;
  for (int i = gtid; i < DD; i += gsz) {
    result[i] = 0.0f;
    xcat[i] = query[i];
    xcat[DD + i] = 0.0f;
  }
  if (gtid < 16) scal[gtid] = (gtid == 4) ? 1.0f : 0.0f;  // active=1
  grid.sync();

  for (int step = 0; step < NSTEPS; ++step) {
    if (vs[4] == 0.0f) break;                 // halted: carry frozen, exit
    const bool hstep = ((step & 3) == 0);

    if (hstep) {
      // h-GRU gates: gi = wih @ [q;l], gh = whh @ h   (24576 rows x 4096)
      for (int r = wid; r < 6 * HH; r += nw) {
        if (r < 3 * HH) {
          float s = dot4((const float4*)h_wih + (size_t)r * 1024,
                         (const float4*)xcat, 1024, lane);
          if (lane == 0) gi_h[r] = s + h_bih[r];
        } else {
          int rr = r - 3 * HH;
          float s = dot4((const float4*)h_whh + (size_t)rr * 1024,
                         (const float4*)cat, 1024, lane);
          if (lane == 0) gh_h[rr] = s + h_bhh[rr];
        }
      }
      grid.sync();
      // h combine
      for (int i = gtid; i < HH; i += gsz) {
        float rr = sigf(gi_h[i] + gh_h[i]);
        float z  = sigf(gi_h[HH + i] + gh_h[HH + i]);
        float nn = tanhf(gi_h[2 * HH + i] + rr * gh_h[2 * HH + i]);
        cat[i] = (1.0f - z) * nn + z * cat[i];
      }
      grid.sync();
      // directive = tanh(dir_w @ h + b) — only changes when h changes
      for (int r = wid; r < DD; r += nw) {
        float s = dot4((const float4*)dir_w + (size_t)r * 1024,
                       (const float4*)cat, 1024, lane);
        if (lane == 0) dir[r] = tanhf(s + dir_b[r]);
      }
      grid.sync();
    }

    // l-GRU gates: gi = wih @ dir, gh = whh @ l   (12288 rows x 2048)
    for (int r = wid; r < 6 * DD; r += nw) {
      if (r < 3 * DD) {
        float s = dot4((const float4*)l_wih + (size_t)r * 512,
                       (const float4*)dir, 512, lane);
        if (lane == 0) gi_l[r] = s + l_bih[r];
      } else {
        int rr = r - 3 * DD;
        float s = dot4((const float4*)l_whh + (size_t)rr * 512,
                       (const float4*)(cat + HH), 512, lane);
        if (lane == 0) gh_l[rr] = s + l_bhh[rr];
      }
    }
    grid.sync();
    // l combine (also mirrors l into xcat for the next h-step)
    for (int i = gtid; i < DD; i += gsz) {
      float rr = sigf(gi_l[i] + gh_l[i]);
      float z  = sigf(gi_l[DD + i] + gh_l[DD + i]);
      float nn = tanhf(gi_l[2 * DD + i] + rr * gh_l[2 * DD + i]);
      float lv = (1.0f - z) * nn + z * cat[HH + i];
      cat[HH + i] = lv;
      xcat[DD + i] = lv;
    }
    grid.sync();
    // res = tanh(out_w @ l + b)
    for (int r = wid; r < DD; r += nw) {
      float s = dot4((const float4*)out_w + (size_t)r * 512,
                     (const float4*)(cat + HH), 512, lane);
      if (lane == 0) res[r] = tanhf(s + out_b[r]);
    }
    grid.sync();
    // scalars + result accumulation (block 0 only; dots parallel across waves)
    if (blockIdx.x == 0) {
      __shared__ float red[4];
      __shared__ float s_p;
      float s = 0.0f;
      if (wib == 0) {
        if (hstep) {                       // raw_conv depends only on h
          for (int i = lane; i < HH; i += 64) s += conv_w[i] * cat[i];
          s = wred(s);
          if (lane == 0) red[0] = s;
        }
      } else if (wib == 1) {
        for (int i = lane; i < HH + DD; i += 64) s += halt_w[i] * cat[i];
        s = wred(s);
        if (lane == 0) red[1] = s;
      } else if (wib == 2) {
        for (int i = lane; i < HH + DD; i += 64) s += reset_w[i] * cat[i];
        s = wred(s);
        if (lane == 0) red[2] = s;
      }
      __syncthreads();
      if (tid == 0) {
        float raw = hstep ? sigf(red[0] + conv_b[0]) : scal[6];
        if (hstep) scal[6] = raw;
        float mom = 0.9f * scal[3] + 0.1f * raw;
        scal[3] = mom;
        float halt = sigf(red[1] + halt_b[0]);
        float cum = scal[0];
        float p = fminf(halt, 1.0f - cum);
        scal[1] += p;                       // weight
        cum += p; scal[0] = cum;
        bool brk = cum > 0.95f;
        float rdot = red[2] + reset_w[HH + DD] * mom + reset_b[0];
        scal[5] = (!brk && (sigf(rdot) > 0.7f) && (step > KK)) ? 1.0f : 0.0f;
        scal[4] = brk ? 0.0f : 1.0f;
        s_p = p;
      }
      __syncthreads();
      float p = s_p;
      for (int i = tid; i < DD; i += 256) result[i] += p * res[i];
      __threadfence();
    }
    grid.sync();
    if (step > KK && vs[5] != 0.0f) {       // uniform across grid
      for (int r = wid; r < DD; r += nw) {
        float s = dot4((const float4*)init_w + (size_t)r * 1024,
                       (const float4*)cat, 1024, lane);
        if (lane == 0) {
          float lv = tanhf(s + init_b[r]);
          cat[HH + r] = lv;
          xcat[DD + r] = lv;
        }
      }
      grid.sync();
    }
  }
  for (int i = gtid; i < DD; i += gsz) out[i] = result[i] / fmaxf(vs[1], 1e-8f);
}

// ---------------- fallback multi-kernel path (round-1, proven) ----------------
__global__ __launch_bounds__(256) void k_matvec(
    const float* __restrict__ W, const float4* __restrict__ x,
    const float* __restrict__ b, float* __restrict__ y,
    int rows, int n4, int act, const float* __restrict__ gate) {
  if (gate && *gate == 0.0f) return;
  int row = (int)((blockIdx.x * blockDim.x + threadIdx.x) >> 6);
  if (row >= rows) return;
  int lane = threadIdx.x & 63;
  float s = dot4((const float4*)W + (size_t)row * n4, x, n4, lane);
  if (lane == 0) {
    s += b[row];
    if (act) s = tanhf(s);
    y[row] = s;
  }
}

__global__ __launch_bounds__(256) void k_hgru_mm(
    const float* __restrict__ wih, const float* __restrict__ whh,
    const float4* __restrict__ xcat4, const float4* __restrict__ h4,
    const float* __restrict__ bih, const float* __restrict__ bhh,
    float* __restrict__ gi, float* __restrict__ gh,
    const float* __restrict__ gate) {
  if (*gate == 0.0f) return;
  int row = (int)((blockIdx.x * blockDim.x + threadIdx.x) >> 6);
  int lane = threadIdx.x & 63;
  if (row < 3 * HH) {
    float s = dot4((const float4*)wih + (size_t)row * 1024, xcat4, 1024, lane);
    if (lane == 0) gi[row] = s + bih[row];
  } else {
    int r = row - 3 * HH;
    if (r >= 3 * HH) return;
    float s = dot4((const float4*)whh + (size_t)r * 1024, h4, 1024, lane);
    if (lane == 0) gh[r] = s + bhh[r];
  }
}

__global__ __launch_bounds__(256) void k_lgru_mm(
    const float* __restrict__ wih, const float* __restrict__ whh,
    const float4* __restrict__ dir4, const float4* __restrict__ l4,
    const float* __restrict__ bih, const float* __restrict__ bhh,
    float* __restrict__ gi, float* __restrict__ gh,
    const float* __restrict__ gate) {
  if (*gate == 0.0f) return;
  int row = (int)((blockIdx.x * blockDim.x + threadIdx.x) >> 6);
  int lane = threadIdx.x & 63;
  if (row < 3 * DD) {
    float s = dot4((const float4*)wih + (size_t)row * 512, dir4, 512, lane);
    if (lane == 0) gi[row] = s + bih[row];
  } else {
    int r = row - 3 * DD;
    if (r >= 3 * DD) return;
    float s = dot4((const float4*)whh + (size_t)r * 512, l4, 512, lane);
    if (lane == 0) gh[r] = s + bhh[r];
  }
}

__global__ __launch_bounds__(256) void k_gru_combine(
    const float* __restrict__ gi, const float* __restrict__ gh,
    float* __restrict__ hl, float* __restrict__ mirror, int n,
    const float* __restrict__ gate) {
  if (*gate == 0.0f) return;
  int i = blockIdx.x * blockDim.x + threadIdx.x;
  if (i >= n) return;
  float r = sigf(gi[i] + gh[i]);
  float z = sigf(gi[n + i] + gh[n + i]);
  float nn = tanhf(gi[2 * n + i] + r * gh[2 * n + i]);
  float v = (1.0f - z) * nn + z * hl[i];
  hl[i] = v;
  if (mirror) mirror[i] = v;
}

__global__ __launch_bounds__(256) void k_finalize(
    float* __restrict__ cat, const float* __restrict__ res,
    const float* __restrict__ conv_w, const float* __restrict__ conv_b,
    const float* __restrict__ halt_w, const float* __restrict__ halt_b,
    const float* __restrict__ reset_w, const float* __restrict__ reset_b,
    float* __restrict__ scal, float* __restrict__ result, int step_idx) {
  __shared__ float red[4];
  __shared__ float s_p;
  int tid = threadIdx.x;
  int lane = tid & 63;
  int wib = tid >> 6;
  bool hstep = ((step_idx & 3) == 0);
  if (scal[4] == 0.0f) {
    if (tid == 0) scal[5] = 0.0f;
    return;
  }
  float s = 0.0f;
  if (wib == 0) {
    if (hstep) {
      for (int i = lane; i < HH; i += 64) s += conv_w[i] * cat[i];
      s = wred(s);
      if (lane == 0) red[0] = s;
    }
  } else if (wib == 1) {
    for (int i = lane; i < HH + DD; i += 64) s += halt_w[i] * cat[i];
    s = wred(s);
    if (lane == 0) red[1] = s;
  } else if (wib == 2) {
    for (int i = lane; i < HH + DD; i += 64) s += reset_w[i] * cat[i];
    s = wred(s);
    if (lane == 0) red[2] = s;
  }
  __syncthreads();
  if (tid == 0) {
    float raw = hstep ? sigf(red[0] + conv_b[0]) : scal[6];
    if (hstep) scal[6] = raw;
    float mom = 0.9f * scal[3] + 0.1f * raw;
    scal[3] = mom;
    float halt = sigf(red[1] + halt_b[0]);
    float cum = scal[0];
    float p = fminf(halt, 1.0f - cum);
    scal[1] += p;
    cum += p; scal[0] = cum;
    bool brk = cum > 0.95f;
    float rdot = red[2] + reset_w[HH + DD] * mom + reset_b[0];
    scal[5] = (!brk && (sigf(rdot) > 0.7f) && (step_idx > KK)) ? 1.0f : 0.0f;
    scal[4] = brk ? 0.0f : 1.0f;
    s_p = p;
  }
  __syncthreads();
  float p = s_p;
  for (int i = tid; i < DD; i += 256) result[i] += p * res[i];
}

__global__ __launch_bounds__(256) void k_init(float* __restrict__ ws,
                                              const float* __restrict__ query) {
  int i = blockIdx.x * blockDim.x + threadIdx.x;
  if (i < 6400) ws[OFF_CAT + i] = 0.0f;
  if (i < DD) {
    ws[OFF_RESULT + i] = 0.0f;
    ws[OFF_XCAT + i] = query[i];
    ws[OFF_XCAT + DD + i] = 0.0f;
  }
  if (i < 16) ws[OFF_SCAL + i] = (i == 4) ? 1.0f : 0.0f;
}

__global__ __launch_bounds__(256) void k_resetl(
    const float* __restrict__ W, const float4* __restrict__ h4,
    const float* __restrict__ b, float* __restrict__ l, float* __restrict__ mirror,
    const float* __restrict__ gate) {
  if (*gate == 0.0f) return;
  int row = (int)((blockIdx.x * blockDim.x + threadIdx.x) >> 6);
  if (row >= DD) return;
  int lane = threadIdx.x & 63;
  float s = dot4((const float4*)W + (size_t)row * 1024, h4, 1024, lane);
  if (lane == 0) {
    float lv = tanhf(s + b[row]);
    l[row] = lv;
    mirror[row] = lv;
  }
}

__global__ __launch_bounds__(256) void k_out(
    const float* __restrict__ result, const float* __restrict__ scal,
    float* __restrict__ out) {
  int i = blockIdx.x * blockDim.x + threadIdx.x;
  if (i < DD) out[i] = result[i] / fmaxf(scal[1], 1e-8f);
}

extern "C" void kernel_launch(void* const* d_in, const int* in_sizes, int n_in,
                              void* d_out, int out_size, void* d_ws, size_t ws_size,
                              hipStream_t stream) {
  const float* query   = (const float*)d_in[0];
  const float* h_wih   = (const float*)d_in[1];
  const float* h_whh   = (const float*)d_in[2];
  const float* h_bih   = (const float*)d_in[3];
  const float* h_bhh   = (const float*)d_in[4];
  const float* l_wih   = (const float*)d_in[5];
  const float* l_whh   = (const float*)d_in[6];
  const float* l_bih   = (const float*)d_in[7];
  const float* l_bhh   = (const float*)d_in[8];
  const float* dir_w   = (const float*)d_in[9];
  const float* dir_b   = (const float*)d_in[10];
  const float* conv_w  = (const float*)d_in[11];
  const float* conv_b  = (const float*)d_in[12];
  const float* out_w   = (const float*)d_in[13];
  const float* out_b   = (const float*)d_in[14];
  const float* halt_w  = (const float*)d_in[15];
  const float* halt_b  = (const float*)d_in[16];
  const float* reset_w = (const float*)d_in[17];
  const float* reset_b = (const float*)d_in[18];
  const float* init_w  = (const float*)d_in[19];
  const float* init_b  = (const float*)d_in[20];

  float* ws  = (float*)d_ws;
  float* out = (float*)d_out;

  int maxb = 0;
  if (hipOccupancyMaxActiveBlocksPerMultiprocessor(&maxb, k_loop, 256, 0) != hipSuccess || maxb < 1)
    maxb = 2;
  long grid = (long)maxb * 256;          // 256 CUs on MI355X
  if (grid > 2048) grid = 2048;

  void* args[] = {
    (void*)&query,
    (void*)&h_wih, (void*)&h_whh, (void*)&h_bih, (void*)&h_bhh,
    (void*)&l_wih, (void*)&l_whh, (void*)&l_bih, (void*)&l_bhh,
    (void*)&dir_w, (void*)&dir_b, (void*)&conv_w, (void*)&conv_b,
    (void*)&out_w, (void*)&out_b, (void*)&halt_w, (void*)&halt_b,
    (void*)&reset_w, (void*)&reset_b, (void*)&init_w, (void*)&init_b,
    (void*)&ws, (void*)&out
  };
  hipError_t err = hipLaunchCooperativeKernel((void*)k_loop, dim3((unsigned)grid),
                                              dim3(256), args, 0, stream);
  if (err == hipSuccess) return;

  // ---- fallback: gated multi-launch path ----
  float* cat    = ws + OFF_CAT;
  float* gi_h   = ws + OFF_GI_H;
  float* gh_h   = ws + OFF_GH_H;
  float* gi_l   = ws + OFF_GI_L;
  float* gh_l   = ws + OFF_GH_L;
  float* dir    = ws + OFF_DIR;
  float* res    = ws + OFF_RES;
  float* result = ws + OFF_RESULT;
  float* scal   = ws + OFF_SCAL;
  float* xcat   = ws + OFF_XCAT;
  float* g_act  = scal + 4;
  float* g_rst  = scal + 5;

  const float4* x4 = (const float4*)xcat;
  const float4* h4 = (const float4*)cat;
  const float4* l4 = (const float4*)(cat + HH);
  const float4* d4 = (const float4*)dir;

  k_init<<<25, 256, 0, stream>>>(ws, query);
  for (int step = 0; step < NSTEPS; ++step) {
    if ((step & 3) == 0) {
      k_hgru_mm<<<6144, 256, 0, stream>>>(h_wih, h_whh, x4, h4, h_bih, h_bhh,
                                          gi_h, gh_h, g_act);
      k_gru_combine<<<16, 256, 0, stream>>>(gi_h, gh_h, cat, (float*)nullptr, HH, g_act);
      k_matvec<<<512, 256, 0, stream>>>(dir_w, h4, dir_b, dir, DD, 1024, 1, g_act);
    }
    k_lgru_mm<<<3072, 256, 0, stream>>>(l_wih, l_whh, d4, l4, l_bih, l_bhh,
                                        gi_l, gh_l, g_act);
    k_gru_combine<<<8, 256, 0, stream>>>(gi_l, gh_l, cat + HH, xcat + DD, DD, g_act);
    k_matvec<<<512, 256, 0, stream>>>(out_w, l4, out_b, res, DD, 512, 1, g_act);
    k_finalize<<<1, 256, 0, stream>>>(cat, res, conv_w, conv_b, halt_w, halt_b,
                                      reset_w, reset_b, scal, result, step);
    if (step > KK)
      k_resetl<<<512, 256, 0, stream>>>(init_w, h4, init_b, cat + HH, xcat + DD, g_rst);
  }
  k_out<<<8, 256, 0, stream>>>(result, scal, out);
}

// Round 3
// 177.219 us; speedup vs baseline: 4.6338x; 4.6338x over previous
//
#include <hip/hip_runtime.h>
#include <hip/hip_cooperative_groups.h>
#include <math.h>

namespace cg = cooperative_groups;

#define DD 2048
#define HH 4096
#define NSTEPS 16
#define KK 4

// workspace float offsets
#define OFF_CAT    0        // h[4096], l[2048] (+pad to 6400)
#define OFF_GI_H   6400     // 12288
#define OFF_GH_H   18688    // 12288
#define OFF_GI_L   30976    // 6144
#define OFF_GH_L   37120    // 6144
#define OFF_DIR    43264    // 2048
#define OFF_RES    45312    // 2048
#define OFF_RESULT 47360    // 2048
#define OFF_SCAL   49408    // [0]cum [1]weight [2]unused [3]mom [4]active [5]do_reset [6]raw_conv [7]p
#define OFF_XCAT   49472    // [q(2048), l(2048)]

static __device__ __forceinline__ float sigf(float x) { return 1.0f / (1.0f + expf(-x)); }

static __device__ __forceinline__ float wred(float s) {
#pragma unroll
  for (int off = 32; off; off >>= 1) s += __shfl_down(s, off);
  return s;
}

// depth-8 dual-stream float4 row-dot: 16 loads in flight, 4 accumulators.
// n4 must be a multiple of 512 (512 or 1024 here).
static __device__ __forceinline__ float dot8(const float4* __restrict__ Wr,
                                             const float4* __restrict__ x,
                                             int n4, int lane) {
  float a0 = 0.f, a1 = 0.f, a2 = 0.f, a3 = 0.f;
  for (int i = lane; i + 448 < n4; i += 512) {
    float4 w0 = Wr[i],       w1 = Wr[i + 64],  w2 = Wr[i + 128], w3 = Wr[i + 192];
    float4 w4 = Wr[i + 256], w5 = Wr[i + 320], w6 = Wr[i + 384], w7 = Wr[i + 448];
    float4 v0 = x[i],        v1 = x[i + 64],   v2 = x[i + 128],  v3 = x[i + 192];
    float4 v4 = x[i + 256],  v5 = x[i + 320],  v6 = x[i + 384],  v7 = x[i + 448];
    a0 = fmaf(w0.x, v0.x, a0); a0 = fmaf(w0.y, v0.y, a0); a0 = fmaf(w0.z, v0.z, a0); a0 = fmaf(w0.w, v0.w, a0);
    a1 = fmaf(w1.x, v1.x, a1); a1 = fmaf(w1.y, v1.y, a1); a1 = fmaf(w1.z, v1.z, a1); a1 = fmaf(w1.w, v1.w, a1);
    a2 = fmaf(w2.x, v2.x, a2); a2 = fmaf(w2.y, v2.y, a2); a2 = fmaf(w2.z, v2.z, a2); a2 = fmaf(w2.w, v2.w, a2);
    a3 = fmaf(w3.x, v3.x, a3); a3 = fmaf(w3.y, v3.y, a3); a3 = fmaf(w3.z, v3.z, a3); a3 = fmaf(w3.w, v3.w, a3);
    a0 = fmaf(w4.x, v4.x, a0); a0 = fmaf(w4.y, v4.y, a0); a0 = fmaf(w4.z, v4.z, a0); a0 = fmaf(w4.w, v4.w, a0);
    a1 = fmaf(w5.x, v5.x, a1); a1 = fmaf(w5.y, v5.y, a1); a1 = fmaf(w5.z, v5.z, a1); a1 = fmaf(w5.w, v5.w, a1);
    a2 = fmaf(w6.x, v6.x, a2); a2 = fmaf(w6.y, v6.y, a2); a2 = fmaf(w6.z, v6.z, a2); a2 = fmaf(w6.w, v6.w, a2);
    a3 = fmaf(w7.x, v7.x, a3); a3 = fmaf(w7.y, v7.y, a3); a3 = fmaf(w7.z, v7.z, a3); a3 = fmaf(w7.w, v7.w, a3);
  }
  return wred((a0 + a1) + (a2 + a3));
}

// generic gated row-block: y[row] = dot(W[row*stride4 : +n4], x) + b[row]
__global__ __launch_bounds__(256) void k_gi(
    const float* __restrict__ W, const float* __restrict__ b,
    const float4* __restrict__ x, float* __restrict__ y,
    int rows, int stride4, int n4, const float* __restrict__ gate) {
  if (gate && *gate == 0.0f) return;
  int row = (int)((blockIdx.x * 256 + threadIdx.x) >> 6);
  if (row >= rows) return;
  int lane = threadIdx.x & 63;
  float s = dot8((const float4*)W + (size_t)row * stride4, x, n4, lane);
  if (lane == 0) y[row] = s + b[row];
}

// generic gated matvec with optional tanh
__global__ __launch_bounds__(256) void k_matvec(
    const float* __restrict__ W, const float4* __restrict__ x,
    const float* __restrict__ b, float* __restrict__ y,
    int rows, int n4, int act, const float* __restrict__ gate) {
  if (gate && *gate == 0.0f) return;
  int row = (int)((blockIdx.x * 256 + threadIdx.x) >> 6);
  if (row >= rows) return;
  int lane = threadIdx.x & 63;
  float s = dot8((const float4*)W + (size_t)row * n4, x, n4, lane);
  if (lane == 0) {
    s += b[row];
    if (act) s = tanhf(s);
    y[row] = s;
  }
}

// step-0 h-combine: h = (1-z)*n with gh == bhh (h was 0); also seed xcat[q]
__global__ __launch_bounds__(256) void s0_hcombine(
    const float* __restrict__ gi, const float* __restrict__ bhh,
    float* __restrict__ cat, const float* __restrict__ query,
    float* __restrict__ xcat) {
  int tid = threadIdx.x;
  for (int i = tid; i < HH; i += 256) {
    float r = sigf(gi[i] + bhh[i]);
    float z = sigf(gi[HH + i] + bhh[HH + i]);
    float n = tanhf(gi[2 * HH + i] + r * bhh[2 * HH + i]);
    cat[i] = (1.0f - z) * n;
  }
  for (int i = tid; i < DD; i += 256) xcat[i] = query[i];
}

// step-0 l-combine + scalar update (l was 0 -> gh_l == bhh_l; cum/weight/mom were 0)
__global__ __launch_bounds__(256) void s0_B(
    const float* __restrict__ gi_l, const float* __restrict__ l_bhh,
    float* __restrict__ cat, float* __restrict__ xcat,
    const float* __restrict__ conv_w, const float* __restrict__ conv_b,
    const float* __restrict__ halt_w, const float* __restrict__ halt_b,
    float* __restrict__ scal) {
  __shared__ float red[2];
  int tid = threadIdx.x, lane = tid & 63, wib = tid >> 6;
  for (int i = tid; i < DD; i += 256) {
    float r = sigf(gi_l[i] + l_bhh[i]);
    float z = sigf(gi_l[DD + i] + l_bhh[DD + i]);
    float n = tanhf(gi_l[2 * DD + i] + r * l_bhh[2 * DD + i]);
    float lv = (1.0f - z) * n;
    cat[HH + i] = lv;
    xcat[DD + i] = lv;
  }
  __syncthreads();
  if (wib == 0) {
    float s = 0.f;
    for (int i = lane; i < HH; i += 64) s += conv_w[i] * cat[i];
    s = wred(s);
    if (lane == 0) red[0] = s;
  } else if (wib == 1) {
    float s = 0.f;
    for (int i = lane; i < HH + DD; i += 64) s += halt_w[i] * cat[i];
    s = wred(s);
    if (lane == 0) red[1] = s;
  }
  __syncthreads();
  if (tid == 0) {
    float raw = sigf(red[0] + conv_b[0]);
    scal[6] = raw;
    scal[3] = 0.1f * raw;                 // mom = 0.9*0 + 0.1*raw
    float halt = sigf(red[1] + halt_b[0]);
    float p = fminf(halt, 1.0f);          // cum was 0
    scal[7] = p;
    scal[1] = p;                          // weight
    scal[0] = p;                          // cum
    scal[4] = (p > 0.95f) ? 0.0f : 1.0f;  // active
    scal[5] = 0.0f;
    scal[2] = 0.0f;
  }
}

// step-1 l-combine + scalar update (gi_l reused from step 0: dir unchanged)
__global__ __launch_bounds__(256) void s1_B(
    const float* __restrict__ gi_l, const float* __restrict__ gh_l,
    float* __restrict__ cat, float* __restrict__ xcat,
    const float* __restrict__ halt_w, const float* __restrict__ halt_b,
    float* __restrict__ scal) {
  __shared__ float red1;
  int tid = threadIdx.x, lane = tid & 63, wib = tid >> 6;
  if (scal[4] == 0.0f) {
    if (tid == 0) scal[7] = 0.0f;
    return;
  }
  for (int i = tid; i < DD; i += 256) {
    float r = sigf(gi_l[i] + gh_l[i]);
    float z = sigf(gi_l[DD + i] + gh_l[DD + i]);
    float n = tanhf(gi_l[2 * DD + i] + r * gh_l[2 * DD + i]);
    float lv = (1.0f - z) * n + z * cat[HH + i];
    cat[HH + i] = lv;
    xcat[DD + i] = lv;
  }
  __syncthreads();
  if (wib == 1) {
    float s = 0.f;
    for (int i = lane; i < HH + DD; i += 64) s += halt_w[i] * cat[i];
    s = wred(s);
    if (lane == 0) red1 = s;
  }
  __syncthreads();
  if (tid == 0) {
    scal[3] = 0.9f * scal[3] + 0.1f * scal[6];   // mom (raw unchanged: h unchanged)
    float halt = sigf(red1 + halt_b[0]);
    float cum = scal[0];
    float p = fminf(halt, 1.0f - cum);
    scal[7] = p;
    scal[1] += p;
    cum += p;
    scal[0] = cum;
    scal[4] = (cum > 0.95f) ? 0.0f : 1.0f;
  }
}

// res = tanh(out_w @ l + b); result = (assign ? p*res : result + p*res)
__global__ __launch_bounds__(256) void k_res_accum(
    const float* __restrict__ out_w, const float* __restrict__ out_b,
    const float* __restrict__ cat, float* __restrict__ result,
    const float* __restrict__ scal, int assign) {
  float p = scal[7];
  if (!assign && p == 0.0f) return;
  int row = (int)((blockIdx.x * 256 + threadIdx.x) >> 6);
  if (row >= DD) return;
  int lane = threadIdx.x & 63;
  float s = dot8((const float4*)out_w + (size_t)row * 512,
                 (const float4*)(cat + HH), 512, lane);
  if (lane == 0) {
    float r = tanhf(s + out_b[row]);
    result[row] = assign ? p * r : result[row] + p * r;
  }
}

__global__ __launch_bounds__(256) void k_out(
    const float* __restrict__ result, const float* __restrict__ scal,
    float* __restrict__ out) {
  int i = blockIdx.x * 256 + threadIdx.x;
  if (i < DD) out[i] = result[i] / fmaxf(scal[1], 1e-8f);
}

// ---------------- cooperative remainder: steps 2..15 ----------------
__global__ __launch_bounds__(256) void k_rest(
    const float* __restrict__ h_wih, const float* __restrict__ h_whh,
    const float* __restrict__ h_bih, const float* __restrict__ h_bhh,
    const float* __restrict__ l_wih, const float* __restrict__ l_whh,
    const float* __restrict__ l_bih, const float* __restrict__ l_bhh,
    const float* __restrict__ dir_w, const float* __restrict__ dir_b,
    const float* __restrict__ conv_w, const float* __restrict__ conv_b,
    const float* __restrict__ out_w, const float* __restrict__ out_b,
    const float* __restrict__ halt_w, const float* __restrict__ halt_b,
    const float* __restrict__ reset_w, const float* __restrict__ reset_b,
    const float* __restrict__ init_w, const float* __restrict__ init_b,
    float* __restrict__ ws) {
  cg::grid_group grid = cg::this_grid();
  const int tid = threadIdx.x, lane = tid & 63, wib = tid >> 6;
  const int nw = (int)(gridDim.x << 2);
  const int wid = (int)((blockIdx.x << 2) | wib);
  const int gtid = (int)(blockIdx.x * 256 + tid);
  const int gsz = (int)(gridDim.x * 256);
  float* cat = ws + OFF_CAT;
  float* gi_h = ws + OFF_GI_H;
  float* gh_h = ws + OFF_GH_H;
  float* gi_l = ws + OFF_GI_L;
  float* gh_l = ws + OFF_GH_L;
  float* dir = ws + OFF_DIR;
  float* res = ws + OFF_RES;
  float* result = ws + OFF_RESULT;
  float* scal = ws + OFF_SCAL;
  float* xcat = ws + OFF_XCAT;
  volatile float* vs = scal;

  for (int step = 2; step < NSTEPS; ++step) {
    if (vs[4] == 0.0f) break;
    const bool hstep = ((step & 3) == 0);
    if (hstep) {
      for (int r = wid; r < 6 * HH; r += nw) {
        if (r < 3 * HH) {
          float s = dot8((const float4*)h_wih + (size_t)r * 1024,
                         (const float4*)xcat, 1024, lane);
          if (lane == 0) gi_h[r] = s + h_bih[r];
        } else {
          int rr = r - 3 * HH;
          float s = dot8((const float4*)h_whh + (size_t)rr * 1024,
                         (const float4*)cat, 1024, lane);
          if (lane == 0) gh_h[rr] = s + h_bhh[rr];
        }
      }
      grid.sync();
      for (int i = gtid; i < HH; i += gsz) {
        float rr = sigf(gi_h[i] + gh_h[i]);
        float z = sigf(gi_h[HH + i] + gh_h[HH + i]);
        float nn = tanhf(gi_h[2 * HH + i] + rr * gh_h[2 * HH + i]);
        cat[i] = (1.0f - z) * nn + z * cat[i];
      }
      grid.sync();
      for (int r = wid; r < DD; r += nw) {
        float s = dot8((const float4*)dir_w + (size_t)r * 1024,
                       (const float4*)cat, 1024, lane);
        if (lane == 0) dir[r] = tanhf(s + dir_b[r]);
      }
      grid.sync();
    }
    {
      const int tot = hstep ? 12288 : 6144;   // gi_l only when dir changed
      for (int r = wid; r < tot; r += nw) {
        if (r < 6144) {
          float s = dot8((const float4*)l_whh + (size_t)r * 512,
                         (const float4*)(cat + HH), 512, lane);
          if (lane == 0) gh_l[r] = s + l_bhh[r];
        } else {
          int rr = r - 6144;
          float s = dot8((const float4*)l_wih + (size_t)rr * 512,
                         (const float4*)dir, 512, lane);
          if (lane == 0) gi_l[rr] = s + l_bih[rr];
        }
      }
    }
    grid.sync();
    for (int i = gtid; i < DD; i += gsz) {
      float rr = sigf(gi_l[i] + gh_l[i]);
      float z = sigf(gi_l[DD + i] + gh_l[DD + i]);
      float nn = tanhf(gi_l[2 * DD + i] + rr * gh_l[2 * DD + i]);
      float lv = (1.0f - z) * nn + z * cat[HH + i];
      cat[HH + i] = lv;
      xcat[DD + i] = lv;
    }
    grid.sync();
    for (int r = wid; r < DD; r += nw) {
      float s = dot8((const float4*)out_w + (size_t)r * 512,
                     (const float4*)(cat + HH), 512, lane);
      if (lane == 0) res[r] = tanhf(s + out_b[r]);
    }
    grid.sync();
    if (blockIdx.x == 0) {
      __shared__ float red[4];
      __shared__ float s_p;
      float s = 0.f;
      if (wib == 0) {
        if (hstep) {
          for (int i = lane; i < HH; i += 64) s += conv_w[i] * cat[i];
          s = wred(s);
          if (lane == 0) red[0] = s;
        }
      } else if (wib == 1) {
        for (int i = lane; i < HH + DD; i += 64) s += halt_w[i] * cat[i];
        s = wred(s);
        if (lane == 0) red[1] = s;
      } else if (wib == 2) {
        for (int i = lane; i < HH + DD; i += 64) s += reset_w[i] * cat[i];
        s = wred(s);
        if (lane == 0) red[2] = s;
      }
      __syncthreads();
      if (tid == 0) {
        float raw = hstep ? sigf(red[0] + conv_b[0]) : scal[6];
        if (hstep) scal[6] = raw;
        float mom = 0.9f * scal[3] + 0.1f * raw;
        scal[3] = mom;
        float halt = sigf(red[1] + halt_b[0]);
        float cum = scal[0];
        float p = fminf(halt, 1.0f - cum);
        scal[1] += p;
        cum += p;
        scal[0] = cum;
        bool brk = cum > 0.95f;
        float rdot = red[2] + reset_w[HH + DD] * mom + reset_b[0];
        scal[5] = (!brk && (sigf(rdot) > 0.7f) && (step > KK)) ? 1.0f : 0.0f;
        scal[4] = brk ? 0.0f : 1.0f;
        s_p = p;
      }
      __syncthreads();
      float p = s_p;
      for (int i = tid; i < DD; i += 256) result[i] += p * res[i];
      __threadfence();
    }
    grid.sync();
    if (step > KK && vs[5] != 0.0f) {
      for (int r = wid; r < DD; r += nw) {
        float s = dot8((const float4*)init_w + (size_t)r * 1024,
                       (const float4*)cat, 1024, lane);
        if (lane == 0) {
          float lv = tanhf(s + init_b[r]);
          cat[HH + r] = lv;
          xcat[DD + r] = lv;
        }
      }
      grid.sync();
    }
  }
}

// ---------------- fallback pieces for steps 2..15 (if coop launch fails) ------
__global__ __launch_bounds__(256) void k_hgru_mm(
    const float* __restrict__ wih, const float* __restrict__ whh,
    const float4* __restrict__ xcat4, const float4* __restrict__ h4,
    const float* __restrict__ bih, const float* __restrict__ bhh,
    float* __restrict__ gi, float* __restrict__ gh,
    const float* __restrict__ gate) {
  if (*gate == 0.0f) return;
  int row = (int)((blockIdx.x * 256 + threadIdx.x) >> 6);
  int lane = threadIdx.x & 63;
  if (row < 3 * HH) {
    float s = dot8((const float4*)wih + (size_t)row * 1024, xcat4, 1024, lane);
    if (lane == 0) gi[row] = s + bih[row];
  } else {
    int r = row - 3 * HH;
    if (r >= 3 * HH) return;
    float s = dot8((const float4*)whh + (size_t)r * 1024, h4, 1024, lane);
    if (lane == 0) gh[r] = s + bhh[r];
  }
}

__global__ __launch_bounds__(256) void k_gru_combine(
    const float* __restrict__ gi, const float* __restrict__ gh,
    float* __restrict__ hl, float* __restrict__ mirror, int n,
    const float* __restrict__ gate) {
  if (*gate == 0.0f) return;
  int i = blockIdx.x * 256 + threadIdx.x;
  if (i >= n) return;
  float r = sigf(gi[i] + gh[i]);
  float z = sigf(gi[n + i] + gh[n + i]);
  float nn = tanhf(gi[2 * n + i] + r * gh[2 * n + i]);
  float v = (1.0f - z) * nn + z * hl[i];
  hl[i] = v;
  if (mirror) mirror[i] = v;
}

__global__ __launch_bounds__(256) void k_finalize(
    float* __restrict__ cat, const float* __restrict__ res,
    const float* __restrict__ conv_w, const float* __restrict__ conv_b,
    const float* __restrict__ halt_w, const float* __restrict__ halt_b,
    const float* __restrict__ reset_w, const float* __restrict__ reset_b,
    float* __restrict__ scal, float* __restrict__ result, int step_idx) {
  __shared__ float red[4];
  __shared__ float s_p;
  int tid = threadIdx.x, lane = tid & 63, wib = tid >> 6;
  bool hstep = ((step_idx & 3) == 0);
  if (scal[4] == 0.0f) {
    if (tid == 0) scal[5] = 0.0f;
    return;
  }
  float s = 0.f;
  if (wib == 0) {
    if (hstep) {
      for (int i = lane; i < HH; i += 64) s += conv_w[i] * cat[i];
      s = wred(s);
      if (lane == 0) red[0] = s;
    }
  } else if (wib == 1) {
    for (int i = lane; i < HH + DD; i += 64) s += halt_w[i] * cat[i];
    s = wred(s);
    if (lane == 0) red[1] = s;
  } else if (wib == 2) {
    for (int i = lane; i < HH + DD; i += 64) s += reset_w[i] * cat[i];
    s = wred(s);
    if (lane == 0) red[2] = s;
  }
  __syncthreads();
  if (tid == 0) {
    float raw = hstep ? sigf(red[0] + conv_b[0]) : scal[6];
    if (hstep) scal[6] = raw;
    float mom = 0.9f * scal[3] + 0.1f * raw;
    scal[3] = mom;
    float halt = sigf(red[1] + halt_b[0]);
    float cum = scal[0];
    float p = fminf(halt, 1.0f - cum);
    scal[1] += p;
    cum += p;
    scal[0] = cum;
    bool brk = cum > 0.95f;
    float rdot = red[2] + reset_w[HH + DD] * mom + reset_b[0];
    scal[5] = (!brk && (sigf(rdot) > 0.7f) && (step_idx > KK)) ? 1.0f : 0.0f;
    scal[4] = brk ? 0.0f : 1.0f;
    s_p = p;
  }
  __syncthreads();
  float p = s_p;
  for (int i = tid; i < DD; i += 256) result[i] += p * res[i];
}

__global__ __launch_bounds__(256) void k_resetl(
    const float* __restrict__ W, const float4* __restrict__ h4,
    const float* __restrict__ b, float* __restrict__ l, float* __restrict__ mirror,
    const float* __restrict__ gate) {
  if (*gate == 0.0f) return;
  int row = (int)((blockIdx.x * 256 + threadIdx.x) >> 6);
  if (row >= DD) return;
  int lane = threadIdx.x & 63;
  float s = dot8((const float4*)W + (size_t)row * 1024, h4, 1024, lane);
  if (lane == 0) {
    float lv = tanhf(s + b[row]);
    l[row] = lv;
    mirror[row] = lv;
  }
}

extern "C" void kernel_launch(void* const* d_in, const int* in_sizes, int n_in,
                              void* d_out, int out_size, void* d_ws, size_t ws_size,
                              hipStream_t stream) {
  const float* query   = (const float*)d_in[0];
  const float* h_wih   = (const float*)d_in[1];
  const float* h_whh   = (const float*)d_in[2];
  const float* h_bih   = (const float*)d_in[3];
  const float* h_bhh   = (const float*)d_in[4];
  const float* l_wih   = (const float*)d_in[5];
  const float* l_whh   = (const float*)d_in[6];
  const float* l_bih   = (const float*)d_in[7];
  const float* l_bhh   = (const float*)d_in[8];
  const float* dir_w   = (const float*)d_in[9];
  const float* dir_b   = (const float*)d_in[10];
  const float* conv_w  = (const float*)d_in[11];
  const float* conv_b  = (const float*)d_in[12];
  const float* out_w   = (const float*)d_in[13];
  const float* out_b   = (const float*)d_in[14];
  const float* halt_w  = (const float*)d_in[15];
  const float* halt_b  = (const float*)d_in[16];
  const float* reset_w = (const float*)d_in[17];
  const float* reset_b = (const float*)d_in[18];
  const float* init_w  = (const float*)d_in[19];
  const float* init_b  = (const float*)d_in[20];

  float* ws = (float*)d_ws;
  float* out = (float*)d_out;
  float* cat = ws + OFF_CAT;
  float* gi_h = ws + OFF_GI_H;
  float* gh_h = ws + OFF_GH_H;
  float* gi_l = ws + OFF_GI_L;
  float* gh_l = ws + OFF_GH_L;
  float* dir = ws + OFF_DIR;
  float* res = ws + OFF_RES;
  float* result = ws + OFF_RESULT;
  float* scal = ws + OFF_SCAL;
  float* xcat = ws + OFF_XCAT;
  float* g_act = scal + 4;
  float* g_rst = scal + 5;

  const float4* q4 = (const float4*)query;
  const float4* h4 = (const float4*)cat;
  const float4* l4 = (const float4*)(cat + HH);
  const float4* d4 = (const float4*)dir;
  const float4* x4 = (const float4*)xcat;

  // ---- step 0 (h=0, l=0 specialization) ----
  // gi_h = h_wih[:, :2048] @ q + bih  (half-row dot; gh_h == bhh, folded)
  k_gi<<<3072, 256, 0, stream>>>(h_wih, h_bih, q4, gi_h, 12288, 1024, 512, (const float*)nullptr);
  s0_hcombine<<<1, 256, 0, stream>>>(gi_h, h_bhh, cat, query, xcat);
  k_matvec<<<512, 256, 0, stream>>>(dir_w, h4, dir_b, dir, DD, 1024, 1, (const float*)nullptr);
  k_gi<<<1536, 256, 0, stream>>>(l_wih, l_bih, d4, gi_l, 6144, 512, 512, (const float*)nullptr);
  s0_B<<<1, 256, 0, stream>>>(gi_l, l_bhh, cat, xcat, conv_w, conv_b, halt_w, halt_b, scal);
  k_res_accum<<<512, 256, 0, stream>>>(out_w, out_b, cat, result, scal, 1);

  // ---- step 1 (h, dir, gi_l unchanged; only gh_l recomputed) ----
  k_gi<<<1536, 256, 0, stream>>>(l_whh, l_bhh, l4, gh_l, 6144, 512, 512, g_act);
  s1_B<<<1, 256, 0, stream>>>(gi_l, gh_l, cat, xcat, halt_w, halt_b, scal);
  k_res_accum<<<512, 256, 0, stream>>>(out_w, out_b, cat, result, scal, 0);

  // ---- steps 2..15: cooperative remainder (usually exits immediately) ----
  int maxb = 0;
  hipError_t err = hipErrorUnknown;
  if (hipOccupancyMaxActiveBlocksPerMultiprocessor(&maxb, k_rest, 256, 0) == hipSuccess && maxb >= 1) {
    long grid = (long)maxb * 256;
    if (grid > 1024) grid = 1024;
    void* args[] = {
      (void*)&h_wih, (void*)&h_whh, (void*)&h_bih, (void*)&h_bhh,
      (void*)&l_wih, (void*)&l_whh, (void*)&l_bih, (void*)&l_bhh,
      (void*)&dir_w, (void*)&dir_b, (void*)&conv_w, (void*)&conv_b,
      (void*)&out_w, (void*)&out_b, (void*)&halt_w, (void*)&halt_b,
      (void*)&reset_w, (void*)&reset_b, (void*)&init_w, (void*)&init_b,
      (void*)&ws
    };
    err = hipLaunchCooperativeKernel((void*)k_rest, dim3((unsigned)grid),
                                     dim3(256), args, 0, stream);
  }
  if (err != hipSuccess) {
    // fallback: gated multi-launch steps 2..15
    for (int step = 2; step < NSTEPS; ++step) {
      if ((step & 3) == 0) {
        k_hgru_mm<<<6144, 256, 0, stream>>>(h_wih, h_whh, x4, h4, h_bih, h_bhh,
                                            gi_h, gh_h, g_act);
        k_gru_combine<<<16, 256, 0, stream>>>(gi_h, gh_h, cat, (float*)nullptr, HH, g_act);
        k_matvec<<<512, 256, 0, stream>>>(dir_w, h4, dir_b, dir, DD, 1024, 1, g_act);
        k_gi<<<1536, 256, 0, stream>>>(l_wih, l_bih, d4, gi_l, 6144, 512, 512, g_act);
      }
      k_gi<<<1536, 256, 0, stream>>>(l_whh, l_bhh, l4, gh_l, 6144, 512, 512, g_act);
      k_gru_combine<<<8, 256, 0, stream>>>(gi_l, gh_l, cat + HH, xcat + DD, DD, g_act);
      k_matvec<<<512, 256, 0, stream>>>(out_w, l4, out_b, res, DD, 512, 1, g_act);
      k_finalize<<<1, 256, 0, stream>>>(cat, res, conv_w, conv_b, halt_w, halt_b,
                                        reset_w, reset_b, scal, result, step);
      if (step > KK)
        k_resetl<<<512, 256, 0, stream>>>(init_w, h4, init_b, cat + HH, xcat + DD, g_rst);
    }
  }
  k_out<<<8, 256, 0, stream>>>(result, scal, out);
}

// Round 4
// 70.756 us; speedup vs baseline: 11.6059x; 2.5046x over previous
//
#include <hip/hip_runtime.h>
#include <math.h>

#define DD 2048
#define HH 4096
#define NSTEPS 16
#define KK 4

// workspace float offsets
#define OFF_CAT    0        // h[4096], l[2048] (+pad to 6400)
#define OFF_GI_H   6400     // 12288
#define OFF_GH_H   18688    // 12288
#define OFF_GI_L   30976    // 6144
#define OFF_GH_L   37120    // 6144
#define OFF_DIR    43264    // 2048
#define OFF_RES    45312    // 2048
#define OFF_RESULT 47360    // 2048
#define OFF_SCAL   49408    // [0]cum [1]weight [2]spare [3]mom [4]active [5]do_reset
                            // [6]raw_conv [7]p [8]conv_dot_raw [9]halt_h_dot
#define OFF_BAR    49440    // 2 x unsigned (grid barrier count, generation)
#define OFF_XCAT   49472    // [q(2048), l(2048)]

static __device__ __forceinline__ float sigf(float x) { return 1.0f / (1.0f + expf(-x)); }

static __device__ __forceinline__ float wred(float s) {
#pragma unroll
  for (int off = 32; off; off >>= 1) s += __shfl_down(s, off);
  return s;
}

// depth-8 dual-stream float4 row-dot: 16 loads in flight, 4 accumulators.
static __device__ __forceinline__ float dot8(const float4* __restrict__ Wr,
                                             const float4* __restrict__ x,
                                             int n4, int lane) {
  float a0 = 0.f, a1 = 0.f, a2 = 0.f, a3 = 0.f;
  for (int i = lane; i + 448 < n4; i += 512) {
    float4 w0 = Wr[i],       w1 = Wr[i + 64],  w2 = Wr[i + 128], w3 = Wr[i + 192];
    float4 w4 = Wr[i + 256], w5 = Wr[i + 320], w6 = Wr[i + 384], w7 = Wr[i + 448];
    float4 v0 = x[i],        v1 = x[i + 64],   v2 = x[i + 128],  v3 = x[i + 192];
    float4 v4 = x[i + 256],  v5 = x[i + 320],  v6 = x[i + 384],  v7 = x[i + 448];
    a0 = fmaf(w0.x, v0.x, a0); a0 = fmaf(w0.y, v0.y, a0); a0 = fmaf(w0.z, v0.z, a0); a0 = fmaf(w0.w, v0.w, a0);
    a1 = fmaf(w1.x, v1.x, a1); a1 = fmaf(w1.y, v1.y, a1); a1 = fmaf(w1.z, v1.z, a1); a1 = fmaf(w1.w, v1.w, a1);
    a2 = fmaf(w2.x, v2.x, a2); a2 = fmaf(w2.y, v2.y, a2); a2 = fmaf(w2.z, v2.z, a2); a2 = fmaf(w2.w, v2.w, a2);
    a3 = fmaf(w3.x, v3.x, a3); a3 = fmaf(w3.y, v3.y, a3); a3 = fmaf(w3.z, v3.z, a3); a3 = fmaf(w3.w, v3.w, a3);
    a0 = fmaf(w4.x, v4.x, a0); a0 = fmaf(w4.y, v4.y, a0); a0 = fmaf(w4.z, v4.z, a0); a0 = fmaf(w4.w, v4.w, a0);
    a1 = fmaf(w5.x, v5.x, a1); a1 = fmaf(w5.y, v5.y, a1); a1 = fmaf(w5.z, v5.z, a1); a1 = fmaf(w5.w, v5.w, a1);
    a2 = fmaf(w6.x, v6.x, a2); a2 = fmaf(w6.y, v6.y, a2); a2 = fmaf(w6.z, v6.z, a2); a2 = fmaf(w6.w, v6.w, a2);
    a3 = fmaf(w7.x, v7.x, a3); a3 = fmaf(w7.y, v7.y, a3); a3 = fmaf(w7.z, v7.z, a3); a3 = fmaf(w7.w, v7.w, a3);
  }
  return wred((a0 + a1) + (a2 + a3));
}

// software grid barrier (sense via generation counter); all blocks must be resident.
static __device__ __forceinline__ void gsync(unsigned* bar, unsigned* gen,
                                             unsigned nblk, unsigned& lg) {
  __syncthreads();
  if (threadIdx.x == 0) {
    __threadfence();
    unsigned arrived = __hip_atomic_fetch_add(bar, 1u, __ATOMIC_ACQ_REL,
                                              __HIP_MEMORY_SCOPE_AGENT);
    if (arrived == nblk - 1) {
      __hip_atomic_store(bar, 0u, __ATOMIC_RELAXED, __HIP_MEMORY_SCOPE_AGENT);
      __hip_atomic_fetch_add(gen, 1u, __ATOMIC_ACQ_REL, __HIP_MEMORY_SCOPE_AGENT);
    } else {
      while (__hip_atomic_load(gen, __ATOMIC_ACQUIRE, __HIP_MEMORY_SCOPE_AGENT) == lg) {
        __builtin_amdgcn_s_sleep(2);
      }
    }
    lg++;
    __threadfence();
  }
  __syncthreads();
}

// generic gated row-block: y[row] = dot(W[row*stride4 : +n4], x) + b[row]
__global__ __launch_bounds__(256) void k_gi(
    const float* __restrict__ W, const float* __restrict__ b,
    const float4* __restrict__ x, float* __restrict__ y,
    int rows, int stride4, int n4, const float* __restrict__ gate) {
  if (gate && *gate == 0.0f) return;
  int row = (int)((blockIdx.x * 256 + threadIdx.x) >> 6);
  if (row >= rows) return;
  int lane = threadIdx.x & 63;
  float s = dot8((const float4*)W + (size_t)row * stride4, x, n4, lane);
  if (lane == 0) y[row] = s + b[row];
}

// step-0 h-combine (gh == bhh since h was 0) + xcat[q] seed + barrier init
__global__ __launch_bounds__(256) void s0_hcombine(
    const float* __restrict__ gi, const float* __restrict__ bhh,
    float* __restrict__ cat, const float* __restrict__ query,
    float* __restrict__ xcat, unsigned* __restrict__ bar) {
  int i = blockIdx.x * 256 + threadIdx.x;
  if (i < HH) {
    float r = sigf(gi[i] + bhh[i]);
    float z = sigf(gi[HH + i] + bhh[HH + i]);
    float n = tanhf(gi[2 * HH + i] + r * bhh[2 * HH + i]);
    cat[i] = (1.0f - z) * n;
  }
  if (i < DD) xcat[i] = query[i];
  if (i < 2) bar[i] = 0u;
}

// dir = tanh(dir_w @ h + b), plus conv raw dot -> scal[8], halt h-part -> scal[9]
// (h is final for steps 0 AND 1 here, so both dots stay valid across both steps)
__global__ __launch_bounds__(256) void k_dir_conv(
    const float* __restrict__ dir_w, const float* __restrict__ dir_b,
    const float* __restrict__ conv_w, const float* __restrict__ halt_w,
    const float* __restrict__ cat, float* __restrict__ dirv,
    float* __restrict__ scal) {
  int w = (int)((blockIdx.x * 256 + threadIdx.x) >> 6);
  int lane = threadIdx.x & 63;
  if (w < DD) {
    float s = dot8((const float4*)dir_w + (size_t)w * 1024, (const float4*)cat, 1024, lane);
    if (lane == 0) dirv[w] = tanhf(s + dir_b[w]);
  } else if (w == DD) {
    float s = dot8((const float4*)conv_w, (const float4*)cat, 1024, lane);
    if (lane == 0) scal[8] = s;
  } else if (w == DD + 1) {
    float s = dot8((const float4*)halt_w, (const float4*)cat, 1024, lane);
    if (lane == 0) scal[9] = s;
  }
}

// step-0: l-combine (gh_l == l_bhh since l was 0) + halt l-part + scalar update
__global__ __launch_bounds__(1024) void s0_B(
    const float* __restrict__ gi_l, const float* __restrict__ l_bhh,
    float* __restrict__ cat, float* __restrict__ xcat,
    const float* __restrict__ conv_b, const float* __restrict__ halt_w,
    const float* __restrict__ halt_b, float* __restrict__ scal) {
  __shared__ float red[16];
  int tid = threadIdx.x, lane = tid & 63, wib = tid >> 6;
  for (int i = tid; i < DD; i += 1024) {
    float r = sigf(gi_l[i] + l_bhh[i]);
    float z = sigf(gi_l[DD + i] + l_bhh[DD + i]);
    float n = tanhf(gi_l[2 * DD + i] + r * l_bhh[2 * DD + i]);
    float lv = (1.0f - z) * n;
    cat[HH + i] = lv;
    xcat[DD + i] = lv;
  }
  __syncthreads();
  float s = 0.f;
  for (int i = tid; i < DD; i += 1024) s += halt_w[HH + i] * cat[HH + i];
  s = wred(s);
  if (lane == 0) red[wib] = s;
  __syncthreads();
  if (tid == 0) {
    float hl = 0.f;
#pragma unroll
    for (int k = 0; k < 16; k++) hl += red[k];
    float raw = sigf(scal[8] + conv_b[0]);
    scal[6] = raw;
    scal[3] = 0.1f * raw;                 // mom = 0.9*0 + 0.1*raw
    float halt = sigf(scal[9] + hl + halt_b[0]);
    float p = fminf(halt, 1.0f);          // cum was 0
    scal[7] = p;
    scal[1] = p;                          // weight
    scal[0] = p;                          // cum
    scal[4] = (p > 0.95f) ? 0.0f : 1.0f;  // active
    scal[5] = 0.0f;
    scal[2] = 0.0f;
  }
}

// step-1: l-combine (gi_l reused: dir unchanged) + halt l-part + scalar update
__global__ __launch_bounds__(1024) void s1_B(
    const float* __restrict__ gi_l, const float* __restrict__ gh_l,
    float* __restrict__ cat, float* __restrict__ xcat,
    const float* __restrict__ halt_b, const float* __restrict__ halt_w,
    float* __restrict__ scal) {
  __shared__ float red[16];
  int tid = threadIdx.x, lane = tid & 63, wib = tid >> 6;
  if (scal[4] == 0.0f) {
    if (tid == 0) scal[7] = 0.0f;
    return;
  }
  for (int i = tid; i < DD; i += 1024) {
    float r = sigf(gi_l[i] + gh_l[i]);
    float z = sigf(gi_l[DD + i] + gh_l[DD + i]);
    float n = tanhf(gi_l[2 * DD + i] + r * gh_l[2 * DD + i]);
    float lv = (1.0f - z) * n + z * cat[HH + i];
    cat[HH + i] = lv;
    xcat[DD + i] = lv;
  }
  __syncthreads();
  float s = 0.f;
  for (int i = tid; i < DD; i += 1024) s += halt_w[HH + i] * cat[HH + i];
  s = wred(s);
  if (lane == 0) red[wib] = s;
  __syncthreads();
  if (tid == 0) {
    float hl = 0.f;
#pragma unroll
    for (int k = 0; k < 16; k++) hl += red[k];
    scal[3] = 0.9f * scal[3] + 0.1f * scal[6];   // raw unchanged (h unchanged)
    float halt = sigf(scal[9] + hl + halt_b[0]);
    float cum = scal[0];
    float p = fminf(halt, 1.0f - cum);
    scal[7] = p;
    scal[1] += p;
    cum += p;
    scal[0] = cum;
    scal[4] = (cum > 0.95f) ? 0.0f : 1.0f;
  }
}

// res = tanh(out_w @ l + b); result = (assign ? p*res : result + p*res)
__global__ __launch_bounds__(256) void k_res_accum(
    const float* __restrict__ out_w, const float* __restrict__ out_b,
    const float* __restrict__ cat, float* __restrict__ result,
    const float* __restrict__ scal, int assign) {
  float p = scal[7];
  if (!assign && p == 0.0f) return;
  int row = (int)((blockIdx.x * 256 + threadIdx.x) >> 6);
  if (row >= DD) return;
  int lane = threadIdx.x & 63;
  float s = dot8((const float4*)out_w + (size_t)row * 512,
                 (const float4*)(cat + HH), 512, lane);
  if (lane == 0) {
    float r = tanhf(s + out_b[row]);
    result[row] = assign ? p * r : result[row] + p * r;
  }
}

__global__ __launch_bounds__(256) void k_out(
    const float* __restrict__ result, const float* __restrict__ scal,
    float* __restrict__ out) {
  int i = blockIdx.x * 256 + threadIdx.x;
  if (i < DD) out[i] = result[i] / fmaxf(scal[1], 1e-8f);
}

// ---- steps 2..15: plain-launch persistent kernel with software grid barrier ----
__global__ __launch_bounds__(256, 2) void k_rest(
    const float* __restrict__ h_wih, const float* __restrict__ h_whh,
    const float* __restrict__ h_bih, const float* __restrict__ h_bhh,
    const float* __restrict__ l_wih, const float* __restrict__ l_whh,
    const float* __restrict__ l_bih, const float* __restrict__ l_bhh,
    const float* __restrict__ dir_w, const float* __restrict__ dir_b,
    const float* __restrict__ conv_w, const float* __restrict__ conv_b,
    const float* __restrict__ out_w, const float* __restrict__ out_b,
    const float* __restrict__ halt_w, const float* __restrict__ halt_b,
    const float* __restrict__ reset_w, const float* __restrict__ reset_b,
    const float* __restrict__ init_w, const float* __restrict__ init_b,
    float* __restrict__ ws, unsigned nblk) {
  const int tid = threadIdx.x, lane = tid & 63, wib = tid >> 6;
  const int nw = (int)(gridDim.x << 2);
  const int wid = (int)((blockIdx.x << 2) | wib);
  const int gtid = (int)(blockIdx.x * 256 + tid);
  const int gsz = (int)(gridDim.x * 256);
  float* cat = ws + OFF_CAT;
  float* gi_h = ws + OFF_GI_H;
  float* gh_h = ws + OFF_GH_H;
  float* gi_l = ws + OFF_GI_L;
  float* gh_l = ws + OFF_GH_L;
  float* dir = ws + OFF_DIR;
  float* res = ws + OFF_RES;
  float* result = ws + OFF_RESULT;
  float* scal = ws + OFF_SCAL;
  float* xcat = ws + OFF_XCAT;
  unsigned* bar = (unsigned*)(ws + OFF_BAR);
  volatile float* vs = scal;
  unsigned lg = 0;

  for (int step = 2; step < NSTEPS; ++step) {
    if (vs[4] == 0.0f) break;
    const bool hstep = ((step & 3) == 0);
    if (hstep) {
      for (int r = wid; r < 6 * HH; r += nw) {
        if (r < 3 * HH) {
          float s = dot8((const float4*)h_wih + (size_t)r * 1024,
                         (const float4*)xcat, 1024, lane);
          if (lane == 0) gi_h[r] = s + h_bih[r];
        } else {
          int rr = r - 3 * HH;
          float s = dot8((const float4*)h_whh + (size_t)rr * 1024,
                         (const float4*)cat, 1024, lane);
          if (lane == 0) gh_h[rr] = s + h_bhh[rr];
        }
      }
      gsync(bar, bar + 1, nblk, lg);
      for (int i = gtid; i < HH; i += gsz) {
        float rr = sigf(gi_h[i] + gh_h[i]);
        float z = sigf(gi_h[HH + i] + gh_h[HH + i]);
        float nn = tanhf(gi_h[2 * HH + i] + rr * gh_h[2 * HH + i]);
        cat[i] = (1.0f - z) * nn + z * cat[i];
      }
      gsync(bar, bar + 1, nblk, lg);
      for (int r = wid; r < DD; r += nw) {
        float s = dot8((const float4*)dir_w + (size_t)r * 1024,
                       (const float4*)cat, 1024, lane);
        if (lane == 0) dir[r] = tanhf(s + dir_b[r]);
      }
      gsync(bar, bar + 1, nblk, lg);
    }
    {
      const int tot = hstep ? 12288 : 6144;   // gi_l only when dir changed
      for (int r = wid; r < tot; r += nw) {
        if (r < 6144) {
          float s = dot8((const float4*)l_whh + (size_t)r * 512,
                         (const float4*)(cat + HH), 512, lane);
          if (lane == 0) gh_l[r] = s + l_bhh[r];
        } else {
          int rr = r - 6144;
          float s = dot8((const float4*)l_wih + (size_t)rr * 512,
                         (const float4*)dir, 512, lane);
          if (lane == 0) gi_l[rr] = s + l_bih[rr];
        }
      }
    }
    gsync(bar, bar + 1, nblk, lg);
    for (int i = gtid; i < DD; i += gsz) {
      float rr = sigf(gi_l[i] + gh_l[i]);
      float z = sigf(gi_l[DD + i] + gh_l[DD + i]);
      float nn = tanhf(gi_l[2 * DD + i] + rr * gh_l[2 * DD + i]);
      float lv = (1.0f - z) * nn + z * cat[HH + i];
      cat[HH + i] = lv;
      xcat[DD + i] = lv;
    }
    gsync(bar, bar + 1, nblk, lg);
    for (int r = wid; r < DD; r += nw) {
      float s = dot8((const float4*)out_w + (size_t)r * 512,
                     (const float4*)(cat + HH), 512, lane);
      if (lane == 0) res[r] = tanhf(s + out_b[r]);
    }
    gsync(bar, bar + 1, nblk, lg);
    if (blockIdx.x == 0) {
      __shared__ float red[4];
      __shared__ float s_p;
      float s = 0.f;
      if (wib == 0) {
        if (hstep) {
          for (int i = lane; i < HH; i += 64) s += conv_w[i] * cat[i];
          s = wred(s);
          if (lane == 0) red[0] = s;
        }
      } else if (wib == 1) {
        for (int i = lane; i < HH + DD; i += 64) s += halt_w[i] * cat[i];
        s = wred(s);
        if (lane == 0) red[1] = s;
      } else if (wib == 2) {
        for (int i = lane; i < HH + DD; i += 64) s += reset_w[i] * cat[i];
        s = wred(s);
        if (lane == 0) red[2] = s;
      }
      __syncthreads();
      if (tid == 0) {
        float raw = hstep ? sigf(red[0] + conv_b[0]) : scal[6];
        if (hstep) scal[6] = raw;
        float mom = 0.9f * scal[3] + 0.1f * raw;
        scal[3] = mom;
        float halt = sigf(red[1] + halt_b[0]);
        float cum = scal[0];
        float p = fminf(halt, 1.0f - cum);
        scal[1] += p;
        cum += p;
        scal[0] = cum;
        bool brk = cum > 0.95f;
        float rdot = red[2] + reset_w[HH + DD] * mom + reset_b[0];
        scal[5] = (!brk && (sigf(rdot) > 0.7f) && (step > KK)) ? 1.0f : 0.0f;
        scal[4] = brk ? 0.0f : 1.0f;
        s_p = p;
      }
      __syncthreads();
      float p = s_p;
      for (int i = tid; i < DD; i += 256) result[i] += p * res[i];
      __threadfence();
    }
    gsync(bar, bar + 1, nblk, lg);
    if (step > KK && vs[5] != 0.0f) {
      for (int r = wid; r < DD; r += nw) {
        float s = dot8((const float4*)init_w + (size_t)r * 1024,
                       (const float4*)cat, 1024, lane);
        if (lane == 0) {
          float lv = tanhf(s + init_b[r]);
          cat[HH + r] = lv;
          xcat[DD + r] = lv;
        }
      }
      gsync(bar, bar + 1, nblk, lg);
    }
  }
}

extern "C" void kernel_launch(void* const* d_in, const int* in_sizes, int n_in,
                              void* d_out, int out_size, void* d_ws, size_t ws_size,
                              hipStream_t stream) {
  const float* query   = (const float*)d_in[0];
  const float* h_wih   = (const float*)d_in[1];
  const float* h_whh   = (const float*)d_in[2];
  const float* h_bih   = (const float*)d_in[3];
  const float* h_bhh   = (const float*)d_in[4];
  const float* l_wih   = (const float*)d_in[5];
  const float* l_whh   = (const float*)d_in[6];
  const float* l_bih   = (const float*)d_in[7];
  const float* l_bhh   = (const float*)d_in[8];
  const float* dir_w   = (const float*)d_in[9];
  const float* dir_b   = (const float*)d_in[10];
  const float* conv_w  = (const float*)d_in[11];
  const float* conv_b  = (const float*)d_in[12];
  const float* out_w   = (const float*)d_in[13];
  const float* out_b   = (const float*)d_in[14];
  const float* halt_w  = (const float*)d_in[15];
  const float* halt_b  = (const float*)d_in[16];
  const float* reset_w = (const float*)d_in[17];
  const float* reset_b = (const float*)d_in[18];
  const float* init_w  = (const float*)d_in[19];
  const float* init_b  = (const float*)d_in[20];

  float* ws = (float*)d_ws;
  float* out = (float*)d_out;
  float* cat = ws + OFF_CAT;
  float* gi_h = ws + OFF_GI_H;
  float* gi_l = ws + OFF_GI_L;
  float* gh_l = ws + OFF_GH_L;
  float* dir = ws + OFF_DIR;
  float* result = ws + OFF_RESULT;
  float* scal = ws + OFF_SCAL;
  float* xcat = ws + OFF_XCAT;
  unsigned* bar = (unsigned*)(ws + OFF_BAR);
  float* g_act = scal + 4;

  const float4* q4 = (const float4*)query;
  const float4* h4 = (const float4*)cat;
  const float4* l4 = (const float4*)(cat + HH);
  const float4* d4 = (const float4*)dir;

  // ---- step 0 (h=0, l=0 specialization) ----
  k_gi<<<3072, 256, 0, stream>>>(h_wih, h_bih, q4, gi_h, 12288, 1024, 512,
                                 (const float*)nullptr);
  s0_hcombine<<<16, 256, 0, stream>>>(gi_h, h_bhh, cat, query, xcat, bar);
  k_dir_conv<<<513, 256, 0, stream>>>(dir_w, dir_b, conv_w, halt_w, cat, dir, scal);
  k_gi<<<1536, 256, 0, stream>>>(l_wih, l_bih, d4, gi_l, 6144, 512, 512,
                                 (const float*)nullptr);
  s0_B<<<1, 1024, 0, stream>>>(gi_l, l_bhh, cat, xcat, conv_b, halt_w, halt_b, scal);
  k_res_accum<<<512, 256, 0, stream>>>(out_w, out_b, cat, result, scal, 1);

  // ---- step 1 (h, dir, gi_l unchanged; only gh_l recomputed) ----
  k_gi<<<1536, 256, 0, stream>>>(l_whh, l_bhh, l4, gh_l, 6144, 512, 512, g_act);
  s1_B<<<1, 1024, 0, stream>>>(gi_l, gh_l, cat, xcat, halt_b, halt_w, scal);
  k_res_accum<<<512, 256, 0, stream>>>(out_w, out_b, cat, result, scal, 0);

  // ---- steps 2..15: software-barrier persistent kernel (usually exits at once) ----
  int maxb = 0;
  if (hipOccupancyMaxActiveBlocksPerMultiprocessor(&maxb, k_rest, 256, 0) != hipSuccess)
    maxb = 1;
  unsigned nblk = (maxb >= 2) ? 512u : 256u;   // guaranteed co-resident
  k_rest<<<nblk, 256, 0, stream>>>(h_wih, h_whh, h_bih, h_bhh,
                                   l_wih, l_whh, l_bih, l_bhh,
                                   dir_w, dir_b, conv_w, conv_b,
                                   out_w, out_b, halt_w, halt_b,
                                   reset_w, reset_b, init_w, init_b,
                                   ws, nblk);

  k_out<<<8, 256, 0, stream>>>(result, scal, out);
}